// Round 7
// baseline (451.487 us; speedup 1.0000x reference)
//
#include <hip/hip_runtime.h>
#include <hip/hip_bf16.h>
#include <stdint.h>

// Problem constants
#define B_   32
#define N_   480
#define DIM_ 1024
#define H_   16
#define D_   64
#define M_   (B_*N_)   // 15360
#define BH_  (B_*H_)   // 512

typedef __bf16 bf16;
typedef __bf16 bf16x4 __attribute__((ext_vector_type(4)));
typedef __bf16 bf16x8 __attribute__((ext_vector_type(8)));
typedef short  short4v __attribute__((ext_vector_type(4)));
typedef float  f32x4  __attribute__((ext_vector_type(4)));

// async global->LDS, 16B per lane; LDS dest = wave-uniform base + lane*16
__device__ __forceinline__ void gld_lds16(const void* g, void* l) {
    using GP = const __attribute__((address_space(1))) unsigned int*;
    using LP = __attribute__((address_space(3))) unsigned int*;
    __builtin_amdgcn_global_load_lds((GP)(uintptr_t)g, (LP)(unsigned int)(uintptr_t)l, 16, 0, 0);
}

// ---------------- fp32 -> bf16 converts ----------------
__global__ void cvt4(const float* __restrict__ in, bf16* __restrict__ out, int n4) {
    int i = blockIdx.x * 256 + threadIdx.x;
    if (i >= n4) return;
    float4 v = ((const float4*)in)[i];
    bf16x4 o = { (bf16)v.x, (bf16)v.y, (bf16)v.z, (bf16)v.w };
    ((bf16x4*)out)[i] = o;
}

__global__ void cvtW(const float* __restrict__ Wq, const float* __restrict__ Wk,
                     const float* __restrict__ Wv, const float* __restrict__ Wo,
                     bf16* __restrict__ Wcat, bf16* __restrict__ Wob) {
    int i = blockIdx.x * 256 + threadIdx.x;
    const float* src; bf16* dst;
    switch (blockIdx.y) {
        case 0: src = Wq; dst = Wcat;                break;
        case 1: src = Wk; dst = Wcat + DIM_*DIM_;    break;
        case 2: src = Wv; dst = Wcat + 2*DIM_*DIM_;  break;
        default: src = Wo; dst = Wob;                break;
    }
    float4 v = ((const float4*)src)[i];
    bf16x4 o = { (bf16)v.x, (bf16)v.y, (bf16)v.z, (bf16)v.w };
    ((bf16x4*)dst)[i] = o;
}

// ======== shared GEMM core: 128x128 tile, BK=64, XOR-swizzled LDS ========
// LDS layout: row r (128B = 8 chunks of 16B); logical chunk c stored at
// physical slot c^(r&7). global_load_lds writes lane->slot `lane` of an
// 8-row group, so lane fetches global chunk (lane&7)^((lane>>3)&7) of row
// (lane>>3). ds_read_b128 fragment reads then hit all 32 banks 2-way (free).
#define GEMM_PRE()                                                            \
    const int tid  = threadIdx.x;                                             \
    const int lane = tid & 63;                                                \
    const int wid  = tid >> 6;                                                \
    const int wm   = wid & 1, wn = wid >> 1;                                  \
    const int m0   = blockIdx.y * 128;                                        \
    const int n0   = blockIdx.x * 128;                                        \
    const int lm   = lane & 15, lq = lane >> 4;                               \
    const int aLane = (lane >> 3) * 1024 + (((lane & 7) ^ (lane >> 3)) & 7) * 8; \
    const bf16* Asrc = A  + (m0 + wid*32) * 1024 + aLane;                     \
    const bf16* Bsrc = Bw + (n0 + wid*32) * 1024 + aLane;                     \
    bf16* AsDst = As + (wid*32)*64;                                           \
    bf16* BsDst = Bs + (wid*32)*64;                                           \
    int rowA[4], rowB[4];                                                     \
    _Pragma("unroll") for (int m = 0; m < 4; ++m) rowA[m] = (wm*64 + m*16 + lm)*64; \
    _Pragma("unroll") for (int n = 0; n < 4; ++n) rowB[n] = (wn*64 + n*16 + lm)*64; \
    const int sw = lm & 7;                                                    \
    int phys[2];                                                              \
    phys[0] = ((lq)     ^ sw) * 8;                                            \
    phys[1] = ((4 + lq) ^ sw) * 8;

#define GEMM_KLOOP(FIRST, SECOND)                                             \
    for (int k0 = 0; k0 < 1024; k0 += 64) {                                   \
        _Pragma("unroll") for (int j = 0; j < 4; ++j) {                       \
            gld_lds16(Asrc + k0 + j*8192, AsDst + j*512);                     \
            gld_lds16(Bsrc + k0 + j*8192, BsDst + j*512);                     \
        }                                                                     \
        __syncthreads();                                                      \
        _Pragma("unroll") for (int ks = 0; ks < 2; ++ks) {                    \
            bf16x8 af[4], bfr[4];                                             \
            _Pragma("unroll") for (int m = 0; m < 4; ++m)                     \
                af[m]  = *(const bf16x8*)&As[rowA[m] + phys[ks]];             \
            _Pragma("unroll") for (int n = 0; n < 4; ++n)                     \
                bfr[n] = *(const bf16x8*)&Bs[rowB[n] + phys[ks]];             \
            _Pragma("unroll") for (int m = 0; m < 4; ++m)                     \
                _Pragma("unroll") for (int n = 0; n < 4; ++n)                 \
                    acc[m][n] = __builtin_amdgcn_mfma_f32_16x16x32_bf16(      \
                        FIRST, SECOND, acc[m][n], 0, 0, 0);                   \
        }                                                                     \
        __syncthreads();                                                      \
    }

// ---------------- QKV projection GEMM ----------------
// C[m,gn] = sum_k A[m,k]*Wcat[gn,k]; Q,K -> [bh][n][d]; V -> [bh][d][n].
// V blocks use swapped MFMA operands (compute C^T) so the transposed store
// is lane-contiguous along n.
__global__ __launch_bounds__(256) void gemm_qkv(const bf16* __restrict__ A, const bf16* __restrict__ Bw,
                                                bf16* __restrict__ Qp, bf16* __restrict__ Kp,
                                                bf16* __restrict__ Vt) {
    __shared__ bf16 As[128*64];
    __shared__ bf16 Bs[128*64];
    GEMM_PRE();
    const int part = n0 >> 10;  // 0=Q,1=K,2=V (block-uniform)
    f32x4 acc[4][4] = {};

    if (part != 2) {
        GEMM_KLOOP(af[m], bfr[n]);
        // C layout: col(gn)=lm, row(gm)=lq*4+r
        bf16* dst = (part == 0) ? Qp : Kp;
        int hh[4], dd[4];
#pragma unroll
        for (int n = 0; n < 4; ++n) {
            int rem = (n0 + wn*64 + n*16 + lm) & 1023;
            hh[n] = rem >> 6; dd[n] = rem & 63;
        }
#pragma unroll
        for (int m = 0; m < 4; ++m) {
#pragma unroll
            for (int r = 0; r < 4; ++r) {
                int gm = m0 + wm*64 + m*16 + lq*4 + r;
                int b  = gm / 480;
                int nn = gm - b*480;
#pragma unroll
                for (int n = 0; n < 4; ++n)
                    dst[((b*16 + hh[n])*480 + nn)*64 + dd[n]] = (bf16)acc[m][n][r];
            }
        }
    } else {
        GEMM_KLOOP(bfr[n], af[m]);
        // C^T layout: col(gm)=lm, row(gn)=lq*4+r -> stores contiguous in nn
#pragma unroll
        for (int m = 0; m < 4; ++m) {
            int gmBase = m0 + wm*64 + m*16;      // lane-uniform; 480%16==0 -> b uniform
            int b  = gmBase / 480;
            int nn = gmBase - b*480 + lm;
#pragma unroll
            for (int n = 0; n < 4; ++n)
#pragma unroll
                for (int r = 0; r < 4; ++r) {
                    int rem = (n0 + wn*64 + n*16 + lq*4 + r) & 1023;
                    int h = rem >> 6, d = rem & 63;
                    Vt[((b*16 + h)*64 + d)*480 + nn] = (bf16)acc[m][n][r];
                }
        }
    }
}

// ---------------- fused attention v9 ----------------
// v8 post-mortem: no spill at 84 VGPR, but 84 > 64 puts waves in the
// 4-waves/SIMD VGPR bucket (waves/CU halve at 64/128); with 6-wave blocks
// that left ~1 resident block (occupancy 17% in BOTH v6 57KB and v8 28KB ->
// LDS was never the limit). v9: 3-wave blocks (192 thr, 48 q rows),
// grid (10,512). At 84-90 VGPR the VGPR cap (16 waves/CU) and LDS cap
// (5 blocks x 28.6KB) now agree: 5 blocks x 3 waves = 15 waves/CU, ~3x v8
// residency, robust to ANY allocation in 65..128. Loop body identical to v8.
//  * K tile: 6 windows; wave w stages windows w, w+3.
//  * V tile: 8 windows (6 real + 2 pad chunks clamped to chunk 5, L2 dup);
//    wave w stages windows w, w+3, and w+6 (waves 0,1 only).
//  * Per iter: barrier -> pe4[3] loads (BEFORE DMAs so pe's vmcnt wait
//    leaves DMAs in flight) -> STAGE(kt+1, buf^1) -> compute buf.
#define KT 48
#define OS_LD 72
__global__ __launch_bounds__(192, 4) void attn(const bf16* __restrict__ Qp, const bf16* __restrict__ Kp,
                                               const bf16* __restrict__ Vt, const float* __restrict__ pe,
                                               bf16* __restrict__ O) {
    __shared__ bf16 Ks[2][KT*64];    // 2 x 6144 B
    __shared__ bf16 Vs[2][64*64];    // 2 x 8192 B
    const int tid  = threadIdx.x;
    const int lane = tid & 63, wid = tid >> 6;   // 3 waves
    const int bh   = blockIdx.y;
    const int b    = bh >> 4, h = bh & 15;
    const int qblk = blockIdx.x * 48;
    const int lm   = lane & 15, lq = lane >> 4;
    const int qbase = bh * (N_ * 64);

    // K staging: window = 8 rows x 8 chunks; lane -> row lane>>3, phys chunk
    // lane&7, fetched logical chunk (lane&7)^(lane>>3).
    const int kROff = (lane >> 3)*64 + ((lane & 7) ^ (lane >> 3))*8;
    // V staging: same lane pattern, logical chunk clamped to 5 (pad slots
    // duplicate chunk 5; readers never map logical c<=5 to a pad slot).
    int cV = (lane & 7) ^ (lane >> 3);
    if (cV > 5) cV = 5;
    int vOffG[3];
#pragma unroll
    for (int i = 0; i < 3; ++i) {
        int j = wid + 3*i;                       // window 0..8 (j=8 skipped)
        vOffG[i] = (bh*64 + j*8 + (lane >> 3))*480 + cV*8;
    }

    // Q fragments (B operand): n=q=lm, k=d
    bf16x8 qb[2];
#pragma unroll
    for (int ks = 0; ks < 2; ++ks)
        qb[ks] = *(const bf16x8*)&Qp[qbase + (qblk + wid*16 + lm)*64 + ks*32 + lq*8];
    const float* peP = pe + (qblk + wid*16 + lm)*480 + lq*4;

    // fragment LDS byte offsets (swizzle folded in)
    int kOff[2];
#pragma unroll
    for (int ks = 0; ks < 2; ++ks) kOff[ks] = ((ks*4 + lq) ^ (lm & 7)) << 4;
    int vOff[3];
#pragma unroll
    for (int mf = 0; mf < 3; ++mf) {
        int c = 2*mf + (lq >> 1);                // logical chunk 0..5
        vOff[mf] = ((c ^ (lm & 7)) << 4) + (lq & 1)*8;
    }

#define STAGE(T, BUF)                                                         \
    {   const bf16* kg = Kp + qbase + (T)*(KT*64) + kROff;                    \
        gld_lds16(kg + wid*512,       (char*)Ks[BUF] + wid*1024);             \
        gld_lds16(kg + (wid+3)*512,   (char*)Ks[BUF] + (wid+3)*1024);         \
        char* vd = (char*)Vs[BUF];                                            \
        gld_lds16(Vt + vOffG[0] + (T)*KT, vd + wid*1024);                     \
        gld_lds16(Vt + vOffG[1] + (T)*KT, vd + (wid+3)*1024);                 \
        if (wid < 2)                                                          \
            gld_lds16(Vt + vOffG[2] + (T)*KT, vd + (wid+6)*1024); }

    STAGE(0, 0);

    f32x4 ot[4] = {};      // O^T accum: m=d (4 frags), n=q
    float lsum = 0.f;

    for (int kt = 0; kt < 10; ++kt) {
        const int cur = kt & 1;
        __syncthreads();                       // drains tile-kt DMA (issued a full phase ago)
        // pe loads first (older than DMAs in vmcnt order -> their waits can't drain DMAs)
        f32x4 pe4[3];
#pragma unroll
        for (int mf = 0; mf < 3; ++mf)
            pe4[mf] = *(const f32x4*)(peP + kt*KT + mf*16);
        if (kt < 9) STAGE(kt + 1, cur ^ 1);    // latency hides under compute
        const char* KsB = (const char*)Ks[cur];
        const char* VsB = (const char*)Vs[cur];

        // S^T = K Q^T; P^T = exp(scale*S^T + pe) packed as 16x16x16 B-frags
        short4v pb[3];
#pragma unroll
        for (int mf = 0; mf < 3; ++mf) {
            f32x4 s = {};
#pragma unroll
            for (int ks = 0; ks < 2; ++ks) {
                bf16x8 ka = *(const bf16x8*)(KsB + (mf*16 + lm)*128 + kOff[ks]);
                s = __builtin_amdgcn_mfma_f32_16x16x32_bf16(ka, qb[ks], s, 0, 0, 0);
            }
            bf16x4 pv;
#pragma unroll
            for (int r = 0; r < 4; ++r) {
                float e = __expf(s[r] * 0.125f + pe4[mf][r]);
                lsum += e;
                pv[r] = (bf16)e;
            }
            pb[mf] = __builtin_bit_cast(short4v, pv);
        }

        // O^T += V^T P^T via 16x16x16 (A = V frags from swizzled Vs rows)
#pragma unroll
        for (int df = 0; df < 4; ++df) {
            const char* vrow = VsB + (df*16 + lm)*128;
#pragma unroll
            for (int mf = 0; mf < 3; ++mf) {
                short4v va = *(const short4v*)(vrow + vOff[mf]);
                ot[df] = __builtin_amdgcn_mfma_f32_16x16x16bf16_1k(va, pb[mf], ot[df], 0, 0, 0);
            }
        }
    }
#undef STAGE

    // softmax denom across the 4 lane-groups holding q=lm
    lsum += __shfl_xor(lsum, 16);
    lsum += __shfl_xor(lsum, 32);
    float rl = 1.f / lsum;

    // transpose O^T -> O via LDS (reuse Vs region: 48*72*2 = 6912 <= 8192)
    __syncthreads();
    bf16* Os = &Vs[0][0];  // [48 q][OS_LD]
#pragma unroll
    for (int df = 0; df < 4; ++df)
#pragma unroll
        for (int r = 0; r < 4; ++r)
            Os[(wid*16 + lm)*OS_LD + df*16 + lq*4 + r] = (bf16)(ot[df][r] * rl);
    __syncthreads();
    for (int c = tid; c < 384; c += 192) {
        int row = c >> 3, d0 = (c & 7) * 8;
        uint4 u = *(const uint4*)&Os[row*OS_LD + d0];
        *(uint4*)&O[(b*480 + qblk + row)*1024 + h*64 + d0] = u;
    }
}

// ---------------- output projection GEMM + bias ----------------
__global__ __launch_bounds__(256) void gemm_out(const bf16* __restrict__ A, const bf16* __restrict__ Bw,
                                                const float* __restrict__ bo, float* __restrict__ out) {
    __shared__ bf16 As[128*64];
    __shared__ bf16 Bs[128*64];
    GEMM_PRE();
    f32x4 acc[4][4] = {};
    GEMM_KLOOP(af[m], bfr[n]);
#pragma unroll
    for (int m = 0; m < 4; ++m)
#pragma unroll
        for (int n = 0; n < 4; ++n)
#pragma unroll
            for (int r = 0; r < 4; ++r) {
                int gm = m0 + wm*64 + m*16 + lq*4 + r;
                int gn = n0 + wn*64 + n*16 + lm;
                out[gm*1024 + gn] = acc[m][n][r] + bo[gn];
            }
}

// ---------------- launcher ----------------
extern "C" void kernel_launch(void* const* d_in, const int* in_sizes, int n_in,
                              void* d_out, int out_size, void* d_ws, size_t ws_size,
                              hipStream_t stream) {
    const float* q  = (const float*)d_in[0];
    const float* Wq = (const float*)d_in[1];
    const float* Wk = (const float*)d_in[2];
    const float* Wv = (const float*)d_in[3];
    const float* pe = (const float*)d_in[4];
    const float* Wo = (const float*)d_in[5];
    const float* bo = (const float*)d_in[6];
    float* out = (float*)d_out;

    char* ws = (char*)d_ws;
    bf16* Abf  = (bf16*)(ws);                         // q bf16 (M x 1024); reused as attn O buffer
    bf16* Wcat = (bf16*)(ws + 31457280);              // 3072 x 1024
    bf16* Wob  = (bf16*)(ws + 31457280 + 6291456);    // 1024 x 1024
    bf16* Qp   = (bf16*)(ws + 39845888);              // [bh][n][d]
    bf16* Kp   = (bf16*)(ws + 71303168);              // [bh][n][d]
    bf16* Vt   = (bf16*)(ws + 102760448);             // [bh][d][n]

    cvt4<<<(M_*DIM_/4 + 255)/256, 256, 0, stream>>>(q, Abf, M_*DIM_/4);
    cvtW<<<dim3(DIM_*DIM_/4/256, 4), 256, 0, stream>>>(Wq, Wk, Wv, Wo, Wcat, Wob);

    gemm_qkv<<<dim3(24, 120), 256, 0, stream>>>(Abf, Wcat, Qp, Kp, Vt);
    attn<<<dim3(10, 512), 192, 0, stream>>>(Qp, Kp, Vt, pe, Abf);
    gemm_out<<<dim3(8, 120), 256, 0, stream>>>(Abf, Wob, bo, out);
}

// Round 8
// 441.821 us; speedup vs baseline: 1.0219x; 1.0219x over previous
//
#include <hip/hip_runtime.h>
#include <hip/hip_bf16.h>
#include <stdint.h>

// Problem constants
#define B_   32
#define N_   480
#define DIM_ 1024
#define H_   16
#define D_   64
#define M_   (B_*N_)   // 15360
#define BH_  (B_*H_)   // 512

typedef __bf16 bf16;
typedef __bf16 bf16x4 __attribute__((ext_vector_type(4)));
typedef __bf16 bf16x8 __attribute__((ext_vector_type(8)));
typedef short  short4v __attribute__((ext_vector_type(4)));
typedef float  f32x4  __attribute__((ext_vector_type(4)));

// async global->LDS, 16B per lane; LDS dest = wave-uniform base + lane*16
__device__ __forceinline__ void gld_lds16(const void* g, void* l) {
    using GP = const __attribute__((address_space(1))) unsigned int*;
    using LP = __attribute__((address_space(3))) unsigned int*;
    __builtin_amdgcn_global_load_lds((GP)(uintptr_t)g, (LP)(unsigned int)(uintptr_t)l, 16, 0, 0);
}

// ---------------- fp32 -> bf16 converts ----------------
__global__ void cvt4(const float* __restrict__ in, bf16* __restrict__ out, int n4) {
    int i = blockIdx.x * 256 + threadIdx.x;
    if (i >= n4) return;
    float4 v = ((const float4*)in)[i];
    bf16x4 o = { (bf16)v.x, (bf16)v.y, (bf16)v.z, (bf16)v.w };
    ((bf16x4*)out)[i] = o;
}

__global__ void cvtW(const float* __restrict__ Wq, const float* __restrict__ Wk,
                     const float* __restrict__ Wv, const float* __restrict__ Wo,
                     bf16* __restrict__ Wcat, bf16* __restrict__ Wob) {
    int i = blockIdx.x * 256 + threadIdx.x;
    const float* src; bf16* dst;
    switch (blockIdx.y) {
        case 0: src = Wq; dst = Wcat;                break;
        case 1: src = Wk; dst = Wcat + DIM_*DIM_;    break;
        case 2: src = Wv; dst = Wcat + 2*DIM_*DIM_;  break;
        default: src = Wo; dst = Wob;                break;
    }
    float4 v = ((const float4*)src)[i];
    bf16x4 o = { (bf16)v.x, (bf16)v.y, (bf16)v.z, (bf16)v.w };
    ((bf16x4*)dst)[i] = o;
}

// ======== shared GEMM core: 128x128 tile, BK=64, XOR-swizzled LDS ========
// LDS layout: row r (128B = 8 chunks of 16B); logical chunk c stored at
// physical slot c^(r&7). global_load_lds writes lane->slot `lane` of an
// 8-row group, so lane fetches global chunk (lane&7)^((lane>>3)&7) of row
// (lane>>3). ds_read_b128 fragment reads then hit all 32 banks 2-way (free).
#define GEMM_PRE()                                                            \
    const int tid  = threadIdx.x;                                             \
    const int lane = tid & 63;                                                \
    const int wid  = tid >> 6;                                                \
    const int wm   = wid & 1, wn = wid >> 1;                                  \
    const int m0   = blockIdx.y * 128;                                        \
    const int n0   = blockIdx.x * 128;                                        \
    const int lm   = lane & 15, lq = lane >> 4;                               \
    const int aLane = (lane >> 3) * 1024 + (((lane & 7) ^ (lane >> 3)) & 7) * 8; \
    const bf16* Asrc = A  + (m0 + wid*32) * 1024 + aLane;                     \
    const bf16* Bsrc = Bw + (n0 + wid*32) * 1024 + aLane;                     \
    bf16* AsDst = As + (wid*32)*64;                                           \
    bf16* BsDst = Bs + (wid*32)*64;                                           \
    int rowA[4], rowB[4];                                                     \
    _Pragma("unroll") for (int m = 0; m < 4; ++m) rowA[m] = (wm*64 + m*16 + lm)*64; \
    _Pragma("unroll") for (int n = 0; n < 4; ++n) rowB[n] = (wn*64 + n*16 + lm)*64; \
    const int sw = lm & 7;                                                    \
    int phys[2];                                                              \
    phys[0] = ((lq)     ^ sw) * 8;                                            \
    phys[1] = ((4 + lq) ^ sw) * 8;

#define GEMM_KLOOP(FIRST, SECOND)                                             \
    for (int k0 = 0; k0 < 1024; k0 += 64) {                                   \
        _Pragma("unroll") for (int j = 0; j < 4; ++j) {                       \
            gld_lds16(Asrc + k0 + j*8192, AsDst + j*512);                     \
            gld_lds16(Bsrc + k0 + j*8192, BsDst + j*512);                     \
        }                                                                     \
        __syncthreads();                                                      \
        _Pragma("unroll") for (int ks = 0; ks < 2; ++ks) {                    \
            bf16x8 af[4], bfr[4];                                             \
            _Pragma("unroll") for (int m = 0; m < 4; ++m)                     \
                af[m]  = *(const bf16x8*)&As[rowA[m] + phys[ks]];             \
            _Pragma("unroll") for (int n = 0; n < 4; ++n)                     \
                bfr[n] = *(const bf16x8*)&Bs[rowB[n] + phys[ks]];             \
            _Pragma("unroll") for (int m = 0; m < 4; ++m)                     \
                _Pragma("unroll") for (int n = 0; n < 4; ++n)                 \
                    acc[m][n] = __builtin_amdgcn_mfma_f32_16x16x32_bf16(      \
                        FIRST, SECOND, acc[m][n], 0, 0, 0);                   \
        }                                                                     \
        __syncthreads();                                                      \
    }

// ---------------- QKV projection GEMM ----------------
// C[m,gn] = sum_k A[m,k]*Wcat[gn,k]; Q,K -> [bh][n][d]; V -> [bh][d][n].
// V blocks use swapped MFMA operands (compute C^T) so the transposed store
// is lane-contiguous along n.
__global__ __launch_bounds__(256) void gemm_qkv(const bf16* __restrict__ A, const bf16* __restrict__ Bw,
                                                bf16* __restrict__ Qp, bf16* __restrict__ Kp,
                                                bf16* __restrict__ Vt) {
    __shared__ bf16 As[128*64];
    __shared__ bf16 Bs[128*64];
    GEMM_PRE();
    const int part = n0 >> 10;  // 0=Q,1=K,2=V (block-uniform)
    f32x4 acc[4][4] = {};

    if (part != 2) {
        GEMM_KLOOP(af[m], bfr[n]);
        // C layout: col(gn)=lm, row(gm)=lq*4+r
        bf16* dst = (part == 0) ? Qp : Kp;
        int hh[4], dd[4];
#pragma unroll
        for (int n = 0; n < 4; ++n) {
            int rem = (n0 + wn*64 + n*16 + lm) & 1023;
            hh[n] = rem >> 6; dd[n] = rem & 63;
        }
#pragma unroll
        for (int m = 0; m < 4; ++m) {
#pragma unroll
            for (int r = 0; r < 4; ++r) {
                int gm = m0 + wm*64 + m*16 + lq*4 + r;
                int b  = gm / 480;
                int nn = gm - b*480;
#pragma unroll
                for (int n = 0; n < 4; ++n)
                    dst[((b*16 + hh[n])*480 + nn)*64 + dd[n]] = (bf16)acc[m][n][r];
            }
        }
    } else {
        GEMM_KLOOP(bfr[n], af[m]);
        // C^T layout: col(gm)=lm, row(gn)=lq*4+r -> stores contiguous in nn
#pragma unroll
        for (int m = 0; m < 4; ++m) {
            int gmBase = m0 + wm*64 + m*16;      // lane-uniform; 480%16==0 -> b uniform
            int b  = gmBase / 480;
            int nn = gmBase - b*480 + lm;
#pragma unroll
            for (int n = 0; n < 4; ++n)
#pragma unroll
                for (int r = 0; r < 4; ++r) {
                    int rem = (n0 + wn*64 + n*16 + lq*4 + r) & 1023;
                    int h = rem >> 6, d = rem & 63;
                    Vt[((b*16 + h)*64 + d)*480 + nn] = (bf16)acc[m][n][r];
                }
        }
    }
}

// ---------------- fused attention v10 ----------------
// Ledger across v3..v9: v3 (5 waves, 80q, reg staging) = 134us @ occ 41%,
// VGPR 40; v6/v8 (DMA dbuf, 6 waves) = occ 17%; v9 (DMA dbuf, 3 waves,
// infeasible bounds) = VGPR 64 + 150MB spill. v10 combines the proven legs:
//  * v3 geometry: 5 waves x 16 q = 80 rows, grid (6,512) -> 6x K/V restage.
//  * v6 staging: zero-register async DMA (global_load_lds) + double buffer.
//  * KT=48 tile; unified smem[2][7168]: per buf [0,3072)=K 48x64,
//    [3072,7168)=V 64 d-rows x 64 keys (48 real + pad dup of chunk 5).
//    All 14 1KB windows land at base + j*1024 (j=0..5 K, 6..13 V).
//  * wave w stages windows {w, w+5, w+10<14}: slot0 always K, slot2 always
//    V, slot1 mixed (wid==0 -> K window 5, else V window wid-1).
//  * v8 bounds semantics: launch_bounds(320,3) -- FEASIBLE guarantee
//    (3 blocks x 28.6KB LDS = 86KB), proven to yield ~84 VGPR w/o spill.
//  * Per iter: barrier -> pe4[3] loads (BEFORE DMAs: older in vmcnt order,
//    their waits can't drain DMAs) -> STAGE(kt+1, buf^1) -> compute buf.
#define KT 48
#define OS_LD 72
__global__ __launch_bounds__(320, 3) void attn(const bf16* __restrict__ Qp, const bf16* __restrict__ Kp,
                                               const bf16* __restrict__ Vt, const float* __restrict__ pe,
                                               bf16* __restrict__ O) {
    __shared__ bf16 smem[2][7168];   // 2 x 14336 B = 28672 B
    const int tid  = threadIdx.x;
    const int lane = tid & 63, wid = tid >> 6;   // 5 waves
    const int bh   = blockIdx.y;
    const int b    = bh >> 4, h = bh & 15;
    const int qblk = blockIdx.x * 80;
    const int lm   = lane & 15, lq = lane >> 4;
    const int qbase = bh * (N_ * 64);

    // K windows: 8 rows x 8 chunks; lane -> row lane>>3, phys chunk lane&7,
    // fetched logical chunk (lane&7)^(lane>>3)  (XOR swizzle, write-linear).
    const int kROff = (lane >> 3)*64 + ((lane & 7) ^ (lane >> 3))*8;
    // V windows: same pattern on [d][key] rows; logical chunk clamped to 5
    // (pad slots duplicate chunk 5; PV only reads logical chunks 0..5).
    int cV = (lane & 7) ^ (lane >> 3);
    if (cV > 5) cV = 5;

    // staging slots (wave-uniform window ids; per-lane global sources)
    const bf16* s0 = Kp + qbase + wid*512 + kROff;            // K window wid
    const int  d0s = wid*1024;
    const bf16* s1; int m1;
    if (wid == 0) { s1 = Kp + qbase + 5*512 + kROff; m1 = 3072; }   // K win 5
    else { int vr = (wid-1)*8 + (lane >> 3);                         // V win wid-1
           s1 = Vt + (bh*64 + vr)*480 + cV*8; m1 = 48; }
    const int  d1s = (wid+5)*1024;
    const bool a2  = wid < 4;                                        // V win wid+4
    int vr2 = (a2 ? (wid+4) : 0)*8 + (lane >> 3);
    const bf16* s2 = Vt + (bh*64 + vr2)*480 + cV*8;
    const int  d2s = (wid+10)*1024;

    // Q fragments (B operand): n=q=lm, k=d
    bf16x8 qb[2];
#pragma unroll
    for (int ks = 0; ks < 2; ++ks)
        qb[ks] = *(const bf16x8*)&Qp[qbase + (qblk + wid*16 + lm)*64 + ks*32 + lq*8];
    const float* peP = pe + (qblk + wid*16 + lm)*480 + lq*4;

    // fragment LDS byte offsets (swizzle folded in)
    int kOff[2];
#pragma unroll
    for (int ks = 0; ks < 2; ++ks) kOff[ks] = ((ks*4 + lq) ^ (lm & 7)) << 4;
    int vOff[3];
#pragma unroll
    for (int mf = 0; mf < 3; ++mf) {
        int c = 2*mf + (lq >> 1);                // logical chunk 0..5
        vOff[mf] = ((c ^ (lm & 7)) << 4) + (lq & 1)*8;
    }

#define STAGE(T, BUF)                                                         \
    {   char* sb = (char*)smem[BUF];                                          \
        gld_lds16(s0 + (T)*3072, sb + d0s);                                   \
        gld_lds16(s1 + (T)*m1,   sb + d1s);                                   \
        if (a2) gld_lds16(s2 + (T)*48, sb + d2s); }

    STAGE(0, 0);

    f32x4 ot[4] = {};      // O^T accum: m=d (4 frags), n=q
    float lsum = 0.f;

    for (int kt = 0; kt < 10; ++kt) {
        const int cur = kt & 1;
        __syncthreads();                       // drains tile-kt DMA (issued a full phase ago)
        // pe loads first (older than DMAs in vmcnt order -> their waits can't drain DMAs)
        f32x4 pe4[3];
#pragma unroll
        for (int mf = 0; mf < 3; ++mf)
            pe4[mf] = *(const f32x4*)(peP + kt*KT + mf*16);
        if (kt < 9) STAGE(kt + 1, cur ^ 1);    // latency hides under compute
        const char* KsB = (const char*)smem[cur];
        const char* VsB = KsB + 6144;

        // S^T = K Q^T; P^T = exp(scale*S^T + pe) packed as 16x16x16 B-frags
        short4v pb[3];
#pragma unroll
        for (int mf = 0; mf < 3; ++mf) {
            f32x4 s = {};
#pragma unroll
            for (int ks = 0; ks < 2; ++ks) {
                bf16x8 ka = *(const bf16x8*)(KsB + (mf*16 + lm)*128 + kOff[ks]);
                s = __builtin_amdgcn_mfma_f32_16x16x32_bf16(ka, qb[ks], s, 0, 0, 0);
            }
            bf16x4 pv;
#pragma unroll
            for (int r = 0; r < 4; ++r) {
                float e = __expf(s[r] * 0.125f + pe4[mf][r]);
                lsum += e;
                pv[r] = (bf16)e;
            }
            pb[mf] = __builtin_bit_cast(short4v, pv);
        }

        // O^T += V^T P^T via 16x16x16 (A = V frags from swizzled Vs rows)
#pragma unroll
        for (int df = 0; df < 4; ++df) {
            const char* vrow = VsB + (df*16 + lm)*128;
#pragma unroll
            for (int mf = 0; mf < 3; ++mf) {
                short4v va = *(const short4v*)(vrow + vOff[mf]);
                ot[df] = __builtin_amdgcn_mfma_f32_16x16x16bf16_1k(va, pb[mf], ot[df], 0, 0, 0);
            }
        }
    }
#undef STAGE

    // softmax denom across the 4 lane-groups holding q=lm
    lsum += __shfl_xor(lsum, 16);
    lsum += __shfl_xor(lsum, 32);
    float rl = 1.f / lsum;

    // transpose O^T -> O via LDS (reuse smem: 80*72*2 = 11520 <= 28672)
    __syncthreads();
    bf16* Os = &smem[0][0];  // [80 q][OS_LD]
#pragma unroll
    for (int df = 0; df < 4; ++df)
#pragma unroll
        for (int r = 0; r < 4; ++r)
            Os[(wid*16 + lm)*OS_LD + df*16 + lq*4 + r] = (bf16)(ot[df][r] * rl);
    __syncthreads();
    for (int c = tid; c < 640; c += 320) {
        int row = c >> 3, d0 = (c & 7) * 8;
        uint4 u = *(const uint4*)&Os[row*OS_LD + d0];
        *(uint4*)&O[(b*480 + qblk + row)*1024 + h*64 + d0] = u;
    }
}

// ---------------- output projection GEMM + bias ----------------
__global__ __launch_bounds__(256) void gemm_out(const bf16* __restrict__ A, const bf16* __restrict__ Bw,
                                                const float* __restrict__ bo, float* __restrict__ out) {
    __shared__ bf16 As[128*64];
    __shared__ bf16 Bs[128*64];
    GEMM_PRE();
    f32x4 acc[4][4] = {};
    GEMM_KLOOP(af[m], bfr[n]);
#pragma unroll
    for (int m = 0; m < 4; ++m)
#pragma unroll
        for (int n = 0; n < 4; ++n)
#pragma unroll
            for (int r = 0; r < 4; ++r) {
                int gm = m0 + wm*64 + m*16 + lq*4 + r;
                int gn = n0 + wn*64 + n*16 + lm;
                out[gm*1024 + gn] = acc[m][n][r] + bo[gn];
            }
}

// ---------------- launcher ----------------
extern "C" void kernel_launch(void* const* d_in, const int* in_sizes, int n_in,
                              void* d_out, int out_size, void* d_ws, size_t ws_size,
                              hipStream_t stream) {
    const float* q  = (const float*)d_in[0];
    const float* Wq = (const float*)d_in[1];
    const float* Wk = (const float*)d_in[2];
    const float* Wv = (const float*)d_in[3];
    const float* pe = (const float*)d_in[4];
    const float* Wo = (const float*)d_in[5];
    const float* bo = (const float*)d_in[6];
    float* out = (float*)d_out;

    char* ws = (char*)d_ws;
    bf16* Abf  = (bf16*)(ws);                         // q bf16 (M x 1024); reused as attn O buffer
    bf16* Wcat = (bf16*)(ws + 31457280);              // 3072 x 1024
    bf16* Wob  = (bf16*)(ws + 31457280 + 6291456);    // 1024 x 1024
    bf16* Qp   = (bf16*)(ws + 39845888);              // [bh][n][d]
    bf16* Kp   = (bf16*)(ws + 71303168);              // [bh][n][d]
    bf16* Vt   = (bf16*)(ws + 102760448);             // [bh][d][n]

    cvt4<<<(M_*DIM_/4 + 255)/256, 256, 0, stream>>>(q, Abf, M_*DIM_/4);
    cvtW<<<dim3(DIM_*DIM_/4/256, 4), 256, 0, stream>>>(Wq, Wk, Wv, Wo, Wcat, Wob);

    gemm_qkv<<<dim3(24, 120), 256, 0, stream>>>(Abf, Wcat, Qp, Kp, Vt);
    attn<<<dim3(6, 512), 320, 0, stream>>>(Qp, Kp, Vt, pe, Abf);
    gemm_out<<<dim3(8, 120), 256, 0, stream>>>(Abf, Wob, bo, out);
}

// Round 9
// 393.609 us; speedup vs baseline: 1.1470x; 1.1225x over previous
//
#include <hip/hip_runtime.h>
#include <hip/hip_bf16.h>
#include <stdint.h>

// Problem constants
#define B_   32
#define N_   480
#define DIM_ 1024
#define H_   16
#define D_   64
#define M_   (B_*N_)   // 15360
#define BH_  (B_*H_)   // 512

typedef __bf16 bf16;
typedef __bf16 bf16x4 __attribute__((ext_vector_type(4)));
typedef __bf16 bf16x8 __attribute__((ext_vector_type(8)));
typedef short  short4v __attribute__((ext_vector_type(4)));
typedef float  f32x4  __attribute__((ext_vector_type(4)));

// async global->LDS, 16B per lane; LDS dest = wave-uniform base + lane*16
__device__ __forceinline__ void gld_lds16(const void* g, void* l) {
    using GP = const __attribute__((address_space(1))) unsigned int*;
    using LP = __attribute__((address_space(3))) unsigned int*;
    __builtin_amdgcn_global_load_lds((GP)(uintptr_t)g, (LP)(unsigned int)(uintptr_t)l, 16, 0, 0);
}

// ---------------- fp32 -> bf16 converts ----------------
__global__ void cvt4(const float* __restrict__ in, bf16* __restrict__ out, int n4) {
    int i = blockIdx.x * 256 + threadIdx.x;
    if (i >= n4) return;
    float4 v = ((const float4*)in)[i];
    bf16x4 o = { (bf16)v.x, (bf16)v.y, (bf16)v.z, (bf16)v.w };
    ((bf16x4*)out)[i] = o;
}

__global__ void cvtW(const float* __restrict__ Wq, const float* __restrict__ Wk,
                     const float* __restrict__ Wv, const float* __restrict__ Wo,
                     bf16* __restrict__ Wcat, bf16* __restrict__ Wob) {
    int i = blockIdx.x * 256 + threadIdx.x;
    const float* src; bf16* dst;
    switch (blockIdx.y) {
        case 0: src = Wq; dst = Wcat;                break;
        case 1: src = Wk; dst = Wcat + DIM_*DIM_;    break;
        case 2: src = Wv; dst = Wcat + 2*DIM_*DIM_;  break;
        default: src = Wo; dst = Wob;                break;
    }
    float4 v = ((const float4*)src)[i];
    bf16x4 o = { (bf16)v.x, (bf16)v.y, (bf16)v.z, (bf16)v.w };
    ((bf16x4*)dst)[i] = o;
}

// ======== shared GEMM core: 128x128 tile, BK=64, XOR-swizzled LDS ========
// LDS layout: row r (128B = 8 chunks of 16B); logical chunk c stored at
// physical slot c^(r&7). global_load_lds writes lane->slot `lane` of an
// 8-row group, so lane fetches global chunk (lane&7)^((lane>>3)&7) of row
// (lane>>3). ds_read_b128 fragment reads then hit all 32 banks 2-way (free).
#define GEMM_PRE()                                                            \
    const int tid  = threadIdx.x;                                             \
    const int lane = tid & 63;                                                \
    const int wid  = tid >> 6;                                                \
    const int wm   = wid & 1, wn = wid >> 1;                                  \
    const int m0   = blockIdx.y * 128;                                        \
    const int n0   = blockIdx.x * 128;                                        \
    const int lm   = lane & 15, lq = lane >> 4;                               \
    const int aLane = (lane >> 3) * 1024 + (((lane & 7) ^ (lane >> 3)) & 7) * 8; \
    const bf16* Asrc = A  + (m0 + wid*32) * 1024 + aLane;                     \
    const bf16* Bsrc = Bw + (n0 + wid*32) * 1024 + aLane;                     \
    bf16* AsDst = As + (wid*32)*64;                                           \
    bf16* BsDst = Bs + (wid*32)*64;                                           \
    int rowA[4], rowB[4];                                                     \
    _Pragma("unroll") for (int m = 0; m < 4; ++m) rowA[m] = (wm*64 + m*16 + lm)*64; \
    _Pragma("unroll") for (int n = 0; n < 4; ++n) rowB[n] = (wn*64 + n*16 + lm)*64; \
    const int sw = lm & 7;                                                    \
    int phys[2];                                                              \
    phys[0] = ((lq)     ^ sw) * 8;                                            \
    phys[1] = ((4 + lq) ^ sw) * 8;

#define GEMM_KLOOP(FIRST, SECOND)                                             \
    for (int k0 = 0; k0 < 1024; k0 += 64) {                                   \
        _Pragma("unroll") for (int j = 0; j < 4; ++j) {                       \
            gld_lds16(Asrc + k0 + j*8192, AsDst + j*512);                     \
            gld_lds16(Bsrc + k0 + j*8192, BsDst + j*512);                     \
        }                                                                     \
        __syncthreads();                                                      \
        _Pragma("unroll") for (int ks = 0; ks < 2; ++ks) {                    \
            bf16x8 af[4], bfr[4];                                             \
            _Pragma("unroll") for (int m = 0; m < 4; ++m)                     \
                af[m]  = *(const bf16x8*)&As[rowA[m] + phys[ks]];             \
            _Pragma("unroll") for (int n = 0; n < 4; ++n)                     \
                bfr[n] = *(const bf16x8*)&Bs[rowB[n] + phys[ks]];             \
            _Pragma("unroll") for (int m = 0; m < 4; ++m)                     \
                _Pragma("unroll") for (int n = 0; n < 4; ++n)                 \
                    acc[m][n] = __builtin_amdgcn_mfma_f32_16x16x32_bf16(      \
                        FIRST, SECOND, acc[m][n], 0, 0, 0);                   \
        }                                                                     \
        __syncthreads();                                                      \
    }

// ---------------- QKV projection GEMM ----------------
// C[m,gn] = sum_k A[m,k]*Wcat[gn,k]; Q,K -> [bh][n][d]; V -> [bh][d][n].
// V blocks use swapped MFMA operands (compute C^T) so the transposed store
// is lane-contiguous along n.
__global__ __launch_bounds__(256) void gemm_qkv(const bf16* __restrict__ A, const bf16* __restrict__ Bw,
                                                bf16* __restrict__ Qp, bf16* __restrict__ Kp,
                                                bf16* __restrict__ Vt) {
    __shared__ bf16 As[128*64];
    __shared__ bf16 Bs[128*64];
    GEMM_PRE();
    const int part = n0 >> 10;  // 0=Q,1=K,2=V (block-uniform)
    f32x4 acc[4][4] = {};

    if (part != 2) {
        GEMM_KLOOP(af[m], bfr[n]);
        // C layout: col(gn)=lm, row(gm)=lq*4+r
        bf16* dst = (part == 0) ? Qp : Kp;
        int hh[4], dd[4];
#pragma unroll
        for (int n = 0; n < 4; ++n) {
            int rem = (n0 + wn*64 + n*16 + lm) & 1023;
            hh[n] = rem >> 6; dd[n] = rem & 63;
        }
#pragma unroll
        for (int m = 0; m < 4; ++m) {
#pragma unroll
            for (int r = 0; r < 4; ++r) {
                int gm = m0 + wm*64 + m*16 + lq*4 + r;
                int b  = gm / 480;
                int nn = gm - b*480;
#pragma unroll
                for (int n = 0; n < 4; ++n)
                    dst[((b*16 + hh[n])*480 + nn)*64 + dd[n]] = (bf16)acc[m][n][r];
            }
        }
    } else {
        GEMM_KLOOP(bfr[n], af[m]);
        // C^T layout: col(gm)=lm, row(gn)=lq*4+r -> stores contiguous in nn
#pragma unroll
        for (int m = 0; m < 4; ++m) {
            int gmBase = m0 + wm*64 + m*16;      // lane-uniform; 480%16==0 -> b uniform
            int b  = gmBase / 480;
            int nn = gmBase - b*480 + lm;
#pragma unroll
            for (int n = 0; n < 4; ++n)
#pragma unroll
                for (int r = 0; r < 4; ++r) {
                    int rem = (n0 + wn*64 + n*16 + lq*4 + r) & 1023;
                    int h = rem >> 6, d = rem & 63;
                    Vt[((b*16 + h)*64 + d)*480 + nn] = (bf16)acc[m][n][r];
                }
        }
    }
}

// ---------------- fused attention v11 ----------------
// Ledger law (v3..v10, 3 independent kernels): VGPR>64 -> ~1 resident
// block/CU on this family (occ 14-17%) regardless of LDS or block size;
// VGPR<=64 -> 12-13 waves. All DMA-dbuf variants needed ~84 VGPR -> pipeline
// ran latency-naked. v11 gets DMA staging UNDER the 64-VGPR cliff:
//  * fully-streamed compute: per mf, QK^T -> exp -> immediately consume in
//    PV. Only ONE P-frag (2 VGPR) + transient pe4 live; no pb[]/pe4[] arrays.
//  * single LDS buffer (KT=96: Ks 96x64=12KB + Vs 64x[128-pad]=16KB = 28KB,
//    5 blocks/CU), GEMM-core 2-barrier pattern: sync -> issue 28 DMA windows
//    -> sync(drain) -> compute. Intra-block the drain serializes; ~25
//    resident waves provide the overlap (m114 mechanism, proven by the GEMM
//    core at 3 blocks/CU).
//  * single-buffer removes the pe/DMA vmcnt-ordering hazard: DMAs are
//    drained before compute, so pe loads sit inside the mf loop (4 VGPR
//    transient).
//  * default launch bounds (v3/v4 precedent: heuristic picks 40-64 when the
//    kernel's natural need allows). Estimated live ~54 VGPR.
// Staging windows (1KB each, 28 total over 5 waves: wave w takes w+5i<28):
//   j<12 : K window j  (rows j*8.., XOR chunk^(r&7), write-linear)
//   j>=12: V window j-12 (4 d-rows x 16 chunks; logical c=(p&8)|((p&7)^(r&7))
//          clamped to 11 -> pad slots hold dup of chunk 11, never read)
#define KT 96
#define OS_LD 72
__global__ __launch_bounds__(320) void attn(const bf16* __restrict__ Qp, const bf16* __restrict__ Kp,
                                            const bf16* __restrict__ Vt, const float* __restrict__ pe,
                                            bf16* __restrict__ O) {
    __shared__ bf16 Ks[KT*64];     // 12288 B
    __shared__ bf16 Vs[64*128];    // 16384 B
    const int tid  = threadIdx.x;
    const int lane = tid & 63, wid = tid >> 6;   // 5 waves
    const int bh   = blockIdx.y;
    const int b    = bh >> 4, h = bh & 15;
    const int qblk = blockIdx.x * 80;
    const int lm   = lane & 15, lq = lane >> 4;
    const int qbase = bh * (N_ * 64);

    // K window per-lane source offset: row lane>>3, fetched chunk (lane&7)^(lane>>3)
    const int kROff = (lane >> 3)*64 + ((lane & 7) ^ (lane >> 3))*8;

    // Q fragments (B operand): n=q=lm, k=d
    bf16x8 qb[2];
#pragma unroll
    for (int ks = 0; ks < 2; ++ks)
        qb[ks] = *(const bf16x8*)&Qp[qbase + (qblk + wid*16 + lm)*64 + ks*32 + lq*8];
    const float* peP = pe + (qblk + wid*16 + lm)*480 + lq*4;

    // fragment LDS byte offsets (swizzle folded in)
    int kOff[2];
#pragma unroll
    for (int ks = 0; ks < 2; ++ks) kOff[ks] = ((ks*4 + lq) ^ (lm & 7)) << 4;

    f32x4 ot[4] = {};      // O^T accum: m=d (4 frags), n=q
    float lsum = 0.f;

    for (int kt = 0; kt < 5; ++kt) {
        __syncthreads();                       // prev tile's LDS readers done
        // issue 28 DMA windows (wave w: j = w+5i < 28)
#pragma unroll
        for (int i = 0; i < 6; ++i) {
            int j = wid + 5*i;                 // wave-uniform
            if (j < 28) {
                if (j < 12) {
                    gld_lds16(Kp + qbase + kt*(KT*64) + j*512 + kROff,
                              (char*)Ks + j*1024);
                } else {
                    int jv = j - 12;
                    int r  = jv*4 + (lane >> 4);
                    int p  = lane & 15;
                    int c  = (p & 8) | ((p & 7) ^ (r & 7));
                    if (c > 11) c = 11;        // pad slots dup chunk 11 (L2 hit)
                    gld_lds16(Vt + (size_t)(bh*64 + r)*480 + kt*KT + c*8,
                              (char*)Vs + jv*1024);
                }
            }
        }
        __syncthreads();                       // drains DMAs (vmcnt(0) before barrier)

        const char* KsB = (const char*)Ks;
        const char* VsB = (const char*)Vs;
        // streamed: per mf, S^T=K Q^T -> P^T=exp(...) -> PV accumulate
#pragma unroll
        for (int mf = 0; mf < 6; ++mf) {
            f32x4 s = {};
#pragma unroll
            for (int ks = 0; ks < 2; ++ks) {
                bf16x8 ka = *(const bf16x8*)(KsB + (mf*16 + lm)*128 + kOff[ks]);
                s = __builtin_amdgcn_mfma_f32_16x16x32_bf16(ka, qb[ks], s, 0, 0, 0);
            }
            f32x4 pe4 = *(const f32x4*)(peP + kt*KT + mf*16);
            bf16x4 pv;
#pragma unroll
            for (int r = 0; r < 4; ++r) {
                float e = __expf(s[r] * 0.125f + pe4[r]);
                lsum += e;
                pv[r] = (bf16)e;
            }
            short4v pb = __builtin_bit_cast(short4v, pv);
            int c = 2*mf + (lq >> 1);          // logical V chunk 0..11
            int vOff = (((c & 8) | ((c & 7) ^ (lm & 7))) << 4) + (lq & 1)*8;
#pragma unroll
            for (int df = 0; df < 4; ++df) {
                short4v va = *(const short4v*)(VsB + (df*16 + lm)*256 + vOff);
                ot[df] = __builtin_amdgcn_mfma_f32_16x16x16bf16_1k(va, pb, ot[df], 0, 0, 0);
            }
        }
    }

    // softmax denom across the 4 lane-groups holding q=lm
    lsum += __shfl_xor(lsum, 16);
    lsum += __shfl_xor(lsum, 32);
    float rl = 1.f / lsum;

    // transpose O^T -> O via LDS (reuse Ks/Vs region: 80*72*2 = 11.5KB)
    __syncthreads();
    bf16* Os = Ks;  // [80 q][OS_LD]
#pragma unroll
    for (int df = 0; df < 4; ++df)
#pragma unroll
        for (int r = 0; r < 4; ++r)
            Os[(wid*16 + lm)*OS_LD + df*16 + lq*4 + r] = (bf16)(ot[df][r] * rl);
    __syncthreads();
    for (int c = tid; c < 640; c += 320) {
        int row = c >> 3, d0 = (c & 7) * 8;
        uint4 u = *(const uint4*)&Os[row*OS_LD + d0];
        *(uint4*)&O[(b*480 + qblk + row)*1024 + h*64 + d0] = u;
    }
}

// ---------------- output projection GEMM + bias ----------------
__global__ __launch_bounds__(256) void gemm_out(const bf16* __restrict__ A, const bf16* __restrict__ Bw,
                                                const float* __restrict__ bo, float* __restrict__ out) {
    __shared__ bf16 As[128*64];
    __shared__ bf16 Bs[128*64];
    GEMM_PRE();
    f32x4 acc[4][4] = {};
    GEMM_KLOOP(af[m], bfr[n]);
#pragma unroll
    for (int m = 0; m < 4; ++m)
#pragma unroll
        for (int n = 0; n < 4; ++n)
#pragma unroll
            for (int r = 0; r < 4; ++r) {
                int gm = m0 + wm*64 + m*16 + lq*4 + r;
                int gn = n0 + wn*64 + n*16 + lm;
                out[gm*1024 + gn] = acc[m][n][r] + bo[gn];
            }
}

// ---------------- launcher ----------------
extern "C" void kernel_launch(void* const* d_in, const int* in_sizes, int n_in,
                              void* d_out, int out_size, void* d_ws, size_t ws_size,
                              hipStream_t stream) {
    const float* q  = (const float*)d_in[0];
    const float* Wq = (const float*)d_in[1];
    const float* Wk = (const float*)d_in[2];
    const float* Wv = (const float*)d_in[3];
    const float* pe = (const float*)d_in[4];
    const float* Wo = (const float*)d_in[5];
    const float* bo = (const float*)d_in[6];
    float* out = (float*)d_out;

    char* ws = (char*)d_ws;
    bf16* Abf  = (bf16*)(ws);                         // q bf16 (M x 1024); reused as attn O buffer
    bf16* Wcat = (bf16*)(ws + 31457280);              // 3072 x 1024
    bf16* Wob  = (bf16*)(ws + 31457280 + 6291456);    // 1024 x 1024
    bf16* Qp   = (bf16*)(ws + 39845888);              // [bh][n][d]
    bf16* Kp   = (bf16*)(ws + 71303168);              // [bh][n][d]
    bf16* Vt   = (bf16*)(ws + 102760448);             // [bh][d][n]

    cvt4<<<(M_*DIM_/4 + 255)/256, 256, 0, stream>>>(q, Abf, M_*DIM_/4);
    cvtW<<<dim3(DIM_*DIM_/4/256, 4), 256, 0, stream>>>(Wq, Wk, Wv, Wo, Wcat, Wob);

    gemm_qkv<<<dim3(24, 120), 256, 0, stream>>>(Abf, Wcat, Qp, Kp, Vt);
    attn<<<dim3(6, 512), 320, 0, stream>>>(Qp, Kp, Vt, pe, Abf);
    gemm_out<<<dim3(8, 120), 256, 0, stream>>>(Abf, Wob, bo, out);
}

// Round 10
// 384.590 us; speedup vs baseline: 1.1739x; 1.0235x over previous
//
#include <hip/hip_runtime.h>
#include <hip/hip_bf16.h>
#include <stdint.h>

// Problem constants
#define B_   32
#define N_   480
#define DIM_ 1024
#define H_   16
#define D_   64
#define M_   (B_*N_)   // 15360
#define BH_  (B_*H_)   // 512

typedef __bf16 bf16;
typedef __bf16 bf16x4 __attribute__((ext_vector_type(4)));
typedef __bf16 bf16x8 __attribute__((ext_vector_type(8)));
typedef short  short4v __attribute__((ext_vector_type(4)));
typedef float  f32x4  __attribute__((ext_vector_type(4)));

// async global->LDS, 16B per lane; LDS dest = wave-uniform base + lane*16
__device__ __forceinline__ void gld_lds16(const void* g, void* l) {
    using GP = const __attribute__((address_space(1))) unsigned int*;
    using LP = __attribute__((address_space(3))) unsigned int*;
    __builtin_amdgcn_global_load_lds((GP)(uintptr_t)g, (LP)(unsigned int)(uintptr_t)l, 16, 0, 0);
}

// ---------------- fp32 -> bf16 converts ----------------
__global__ void cvt4(const float* __restrict__ in, bf16* __restrict__ out, int n4) {
    int i = blockIdx.x * 256 + threadIdx.x;
    if (i >= n4) return;
    float4 v = ((const float4*)in)[i];
    bf16x4 o = { (bf16)v.x, (bf16)v.y, (bf16)v.z, (bf16)v.w };
    ((bf16x4*)out)[i] = o;
}

__global__ void cvtW(const float* __restrict__ Wq, const float* __restrict__ Wk,
                     const float* __restrict__ Wv, const float* __restrict__ Wo,
                     bf16* __restrict__ Wcat, bf16* __restrict__ Wob) {
    int i = blockIdx.x * 256 + threadIdx.x;
    const float* src; bf16* dst;
    switch (blockIdx.y) {
        case 0: src = Wq; dst = Wcat;                break;
        case 1: src = Wk; dst = Wcat + DIM_*DIM_;    break;
        case 2: src = Wv; dst = Wcat + 2*DIM_*DIM_;  break;
        default: src = Wo; dst = Wob;                break;
    }
    float4 v = ((const float4*)src)[i];
    bf16x4 o = { (bf16)v.x, (bf16)v.y, (bf16)v.z, (bf16)v.w };
    ((bf16x4*)dst)[i] = o;
}

// ======== shared GEMM core: 128x128 tile, BK=64, XOR-swizzled LDS ========
// LDS layout: row r (128B = 8 chunks of 16B); logical chunk c stored at
// physical slot c^(r&7). global_load_lds writes lane->slot `lane` of an
// 8-row group, so lane fetches global chunk (lane&7)^((lane>>3)&7) of row
// (lane>>3). ds_read_b128 fragment reads then hit all 32 banks 2-way (free).
#define GEMM_PRE()                                                            \
    const int tid  = threadIdx.x;                                             \
    const int lane = tid & 63;                                                \
    const int wid  = tid >> 6;                                                \
    const int wm   = wid & 1, wn = wid >> 1;                                  \
    const int m0   = blockIdx.y * 128;                                        \
    const int n0   = blockIdx.x * 128;                                        \
    const int lm   = lane & 15, lq = lane >> 4;                               \
    const int aLane = (lane >> 3) * 1024 + (((lane & 7) ^ (lane >> 3)) & 7) * 8; \
    const bf16* Asrc = A  + (m0 + wid*32) * 1024 + aLane;                     \
    const bf16* Bsrc = Bw + (n0 + wid*32) * 1024 + aLane;                     \
    bf16* AsDst = As + (wid*32)*64;                                           \
    bf16* BsDst = Bs + (wid*32)*64;                                           \
    int rowA[4], rowB[4];                                                     \
    _Pragma("unroll") for (int m = 0; m < 4; ++m) rowA[m] = (wm*64 + m*16 + lm)*64; \
    _Pragma("unroll") for (int n = 0; n < 4; ++n) rowB[n] = (wn*64 + n*16 + lm)*64; \
    const int sw = lm & 7;                                                    \
    int phys[2];                                                              \
    phys[0] = ((lq)     ^ sw) * 8;                                            \
    phys[1] = ((4 + lq) ^ sw) * 8;

#define GEMM_KLOOP(FIRST, SECOND)                                             \
    for (int k0 = 0; k0 < 1024; k0 += 64) {                                   \
        _Pragma("unroll") for (int j = 0; j < 4; ++j) {                       \
            gld_lds16(Asrc + k0 + j*8192, AsDst + j*512);                     \
            gld_lds16(Bsrc + k0 + j*8192, BsDst + j*512);                     \
        }                                                                     \
        __syncthreads();                                                      \
        _Pragma("unroll") for (int ks = 0; ks < 2; ++ks) {                    \
            bf16x8 af[4], bfr[4];                                             \
            _Pragma("unroll") for (int m = 0; m < 4; ++m)                     \
                af[m]  = *(const bf16x8*)&As[rowA[m] + phys[ks]];             \
            _Pragma("unroll") for (int n = 0; n < 4; ++n)                     \
                bfr[n] = *(const bf16x8*)&Bs[rowB[n] + phys[ks]];             \
            _Pragma("unroll") for (int m = 0; m < 4; ++m)                     \
                _Pragma("unroll") for (int n = 0; n < 4; ++n)                 \
                    acc[m][n] = __builtin_amdgcn_mfma_f32_16x16x32_bf16(      \
                        FIRST, SECOND, acc[m][n], 0, 0, 0);                   \
        }                                                                     \
        __syncthreads();                                                      \
    }

// ---------------- QKV projection GEMM ----------------
// C[m,gn] = sum_k A[m,k]*Wcat[gn,k]; Q,K -> [bh][n][d]; V -> [bh][d][n].
// V blocks use swapped MFMA operands (compute C^T) so the transposed store
// is lane-contiguous along n.
__global__ __launch_bounds__(256) void gemm_qkv(const bf16* __restrict__ A, const bf16* __restrict__ Bw,
                                                bf16* __restrict__ Qp, bf16* __restrict__ Kp,
                                                bf16* __restrict__ Vt) {
    __shared__ bf16 As[128*64];
    __shared__ bf16 Bs[128*64];
    GEMM_PRE();
    const int part = n0 >> 10;  // 0=Q,1=K,2=V (block-uniform)
    f32x4 acc[4][4] = {};

    if (part != 2) {
        GEMM_KLOOP(af[m], bfr[n]);
        // C layout: col(gn)=lm, row(gm)=lq*4+r
        bf16* dst = (part == 0) ? Qp : Kp;
        int hh[4], dd[4];
#pragma unroll
        for (int n = 0; n < 4; ++n) {
            int rem = (n0 + wn*64 + n*16 + lm) & 1023;
            hh[n] = rem >> 6; dd[n] = rem & 63;
        }
#pragma unroll
        for (int m = 0; m < 4; ++m) {
#pragma unroll
            for (int r = 0; r < 4; ++r) {
                int gm = m0 + wm*64 + m*16 + lq*4 + r;
                int b  = gm / 480;
                int nn = gm - b*480;
#pragma unroll
                for (int n = 0; n < 4; ++n)
                    dst[((b*16 + hh[n])*480 + nn)*64 + dd[n]] = (bf16)acc[m][n][r];
            }
        }
    } else {
        GEMM_KLOOP(bfr[n], af[m]);
        // C^T layout: col(gm)=lm, row(gn)=lq*4+r -> stores contiguous in nn
#pragma unroll
        for (int m = 0; m < 4; ++m) {
            int gmBase = m0 + wm*64 + m*16;      // lane-uniform; 480%16==0 -> b uniform
            int b  = gmBase / 480;
            int nn = gmBase - b*480 + lm;
#pragma unroll
            for (int n = 0; n < 4; ++n)
#pragma unroll
                for (int r = 0; r < 4; ++r) {
                    int rem = (n0 + wn*64 + n*16 + lq*4 + r) & 1023;
                    int h = rem >> 6, d = rem & 63;
                    Vt[((b*16 + h)*64 + d)*480 + nn] = (bf16)acc[m][n][r];
                }
        }
    }
}

// ---------------- fused attention v12 ----------------
// v11 (streamed, single-buffer, ~116us) still pays a naked per-tile DMA
// drain: {issue DMAs -> barrier(vmcnt0) -> compute} serializes the HBM/L2
// latency inside each block. v12 = v11 streaming + DOUBLE BUFFER at the SAME
// 28672B LDS footprint by halving the tile (KT=48, the v8/v9 refcheck-proven
// layout): 2 x (Ks 6KB + Vs 8KB). One barrier per tile; the compiler's
// automatic vmcnt(0)-before-barrier now drains DMAs issued a FULL compute
// phase earlier (T14 mechanism) -> drain cost ~0.
//  * per tile: 14 1KB DMA windows over 5 waves (j=wid+5i<14): j<6 K window j,
//    else V window j-6. K: row lane>>3, fetched chunk (lane&7)^(lane>>3).
//    V: r=jv*8+(lane>>3), logical chunk clamped to 5 (pads dup chunk 5).
//  * pe4[3] loaded right after the barrier, BEFORE the next-tile DMAs:
//    in-order vmcnt retirement means consuming pe never waits on the DMAs.
//  * streamed compute per mf: QK^T -> exp -> PV (no pb[] arrays); VGPR stays
//    near v11's allocation (+8 for pe4).
#define KT 48
#define OS_LD 72
__global__ __launch_bounds__(320) void attn(const bf16* __restrict__ Qp, const bf16* __restrict__ Kp,
                                            const bf16* __restrict__ Vt, const float* __restrict__ pe,
                                            bf16* __restrict__ O) {
    __shared__ bf16 Ks[2][KT*64];    // 2 x 6144 B
    __shared__ bf16 Vs[2][64*64];    // 2 x 8192 B
    const int tid  = threadIdx.x;
    const int lane = tid & 63, wid = tid >> 6;   // 5 waves
    const int bh   = blockIdx.y;
    const int b    = bh >> 4, h = bh & 15;
    const int qblk = blockIdx.x * 80;
    const int lm   = lane & 15, lq = lane >> 4;
    const int qbase = bh * (N_ * 64);

    // K window per-lane source offset: row lane>>3, fetched chunk (lane&7)^(lane>>3)
    const int kROff = (lane >> 3)*64 + ((lane & 7) ^ (lane >> 3))*8;
    // V: logical chunk clamped to 5 (pad slots dup chunk 5, never read)
    int cV = (lane & 7) ^ (lane >> 3);
    if (cV > 5) cV = 5;
    const int cVoff = cV*8;

    // Q fragments (B operand): n=q=lm, k=d
    bf16x8 qb[2];
#pragma unroll
    for (int ks = 0; ks < 2; ++ks)
        qb[ks] = *(const bf16x8*)&Qp[qbase + (qblk + wid*16 + lm)*64 + ks*32 + lq*8];
    const float* peP = pe + (qblk + wid*16 + lm)*480 + lq*4;

    // fragment LDS byte offsets (swizzle folded in)
    int kOff[2];
#pragma unroll
    for (int ks = 0; ks < 2; ++ks) kOff[ks] = ((ks*4 + lq) ^ (lm & 7)) << 4;
    int vOff[3];
#pragma unroll
    for (int mf = 0; mf < 3; ++mf) {
        int c = 2*mf + (lq >> 1);                // logical chunk 0..5
        vOff[mf] = ((c ^ (lm & 7)) << 4) + (lq & 1)*8;
    }

#define STAGE(T, BUF)                                                         \
    _Pragma("unroll")                                                         \
    for (int i = 0; i < 3; ++i) {                                             \
        int j = wid + 5*i;                     /* wave-uniform */             \
        if (j < 14) {                                                         \
            if (j < 6) {                                                      \
                gld_lds16(Kp + qbase + (T)*3072 + j*512 + kROff,              \
                          (char*)Ks[BUF] + j*1024);                           \
            } else {                                                          \
                int jv = j - 6;                                               \
                int r  = jv*8 + (lane >> 3);                                  \
                gld_lds16(Vt + (size_t)(bh*64 + r)*480 + (T)*KT + cVoff,      \
                          (char*)Vs[BUF] + jv*1024);                          \
            }                                                                 \
        }                                                                     \
    }

    STAGE(0, 0);

    f32x4 ot[4] = {};      // O^T accum: m=d (4 frags), n=q
    float lsum = 0.f;

    for (int kt = 0; kt < 10; ++kt) {
        const int cur = kt & 1;
        // barrier: (a) compiler drains vmcnt -> tile-kt DMAs (issued a full
        // phase ago) have landed in ALL waves; (b) buf^1's readers are done.
        __syncthreads();
        // pe loads for THIS tile, issued BEFORE next-tile DMAs (older in
        // vmcnt order -> consuming pe can't force a DMA drain)
        f32x4 pe4[3];
#pragma unroll
        for (int mf = 0; mf < 3; ++mf)
            pe4[mf] = *(const f32x4*)(peP + kt*KT + mf*16);
        if (kt < 9) STAGE(kt + 1, cur ^ 1);    // latency hides under compute
        const char* KsB = (const char*)Ks[cur];
        const char* VsB = (const char*)Vs[cur];

        // streamed: per mf, S^T=K Q^T -> P^T=exp(...) -> PV accumulate
#pragma unroll
        for (int mf = 0; mf < 3; ++mf) {
            f32x4 s = {};
#pragma unroll
            for (int ks = 0; ks < 2; ++ks) {
                bf16x8 ka = *(const bf16x8*)(KsB + (mf*16 + lm)*128 + kOff[ks]);
                s = __builtin_amdgcn_mfma_f32_16x16x32_bf16(ka, qb[ks], s, 0, 0, 0);
            }
            bf16x4 pv;
#pragma unroll
            for (int r = 0; r < 4; ++r) {
                float e = __expf(s[r] * 0.125f + pe4[mf][r]);
                lsum += e;
                pv[r] = (bf16)e;
            }
            short4v pb = __builtin_bit_cast(short4v, pv);
#pragma unroll
            for (int df = 0; df < 4; ++df) {
                short4v va = *(const short4v*)(VsB + (df*16 + lm)*128 + vOff[mf]);
                ot[df] = __builtin_amdgcn_mfma_f32_16x16x16bf16_1k(va, pb, ot[df], 0, 0, 0);
            }
        }
    }
#undef STAGE

    // softmax denom across the 4 lane-groups holding q=lm
    lsum += __shfl_xor(lsum, 16);
    lsum += __shfl_xor(lsum, 32);
    float rl = 1.f / lsum;

    // transpose O^T -> O via LDS (reuse Ks region: 80*72*2 = 11520 <= 12288)
    __syncthreads();
    bf16* Os = &Ks[0][0];  // [80 q][OS_LD]
#pragma unroll
    for (int df = 0; df < 4; ++df)
#pragma unroll
        for (int r = 0; r < 4; ++r)
            Os[(wid*16 + lm)*OS_LD + df*16 + lq*4 + r] = (bf16)(ot[df][r] * rl);
    __syncthreads();
    for (int c = tid; c < 640; c += 320) {
        int row = c >> 3, d0 = (c & 7) * 8;
        uint4 u = *(const uint4*)&Os[row*OS_LD + d0];
        *(uint4*)&O[(b*480 + qblk + row)*1024 + h*64 + d0] = u;
    }
}

// ---------------- output projection GEMM + bias ----------------
__global__ __launch_bounds__(256) void gemm_out(const bf16* __restrict__ A, const bf16* __restrict__ Bw,
                                                const float* __restrict__ bo, float* __restrict__ out) {
    __shared__ bf16 As[128*64];
    __shared__ bf16 Bs[128*64];
    GEMM_PRE();
    f32x4 acc[4][4] = {};
    GEMM_KLOOP(af[m], bfr[n]);
#pragma unroll
    for (int m = 0; m < 4; ++m)
#pragma unroll
        for (int n = 0; n < 4; ++n)
#pragma unroll
            for (int r = 0; r < 4; ++r) {
                int gm = m0 + wm*64 + m*16 + lq*4 + r;
                int gn = n0 + wn*64 + n*16 + lm;
                out[gm*1024 + gn] = acc[m][n][r] + bo[gn];
            }
}

// ---------------- launcher ----------------
extern "C" void kernel_launch(void* const* d_in, const int* in_sizes, int n_in,
                              void* d_out, int out_size, void* d_ws, size_t ws_size,
                              hipStream_t stream) {
    const float* q  = (const float*)d_in[0];
    const float* Wq = (const float*)d_in[1];
    const float* Wk = (const float*)d_in[2];
    const float* Wv = (const float*)d_in[3];
    const float* pe = (const float*)d_in[4];
    const float* Wo = (const float*)d_in[5];
    const float* bo = (const float*)d_in[6];
    float* out = (float*)d_out;

    char* ws = (char*)d_ws;
    bf16* Abf  = (bf16*)(ws);                         // q bf16 (M x 1024); reused as attn O buffer
    bf16* Wcat = (bf16*)(ws + 31457280);              // 3072 x 1024
    bf16* Wob  = (bf16*)(ws + 31457280 + 6291456);    // 1024 x 1024
    bf16* Qp   = (bf16*)(ws + 39845888);              // [bh][n][d]
    bf16* Kp   = (bf16*)(ws + 71303168);              // [bh][n][d]
    bf16* Vt   = (bf16*)(ws + 102760448);             // [bh][d][n]

    cvt4<<<(M_*DIM_/4 + 255)/256, 256, 0, stream>>>(q, Abf, M_*DIM_/4);
    cvtW<<<dim3(DIM_*DIM_/4/256, 4), 256, 0, stream>>>(Wq, Wk, Wv, Wo, Wcat, Wob);

    gemm_qkv<<<dim3(24, 120), 256, 0, stream>>>(Abf, Wcat, Qp, Kp, Vt);
    attn<<<dim3(6, 512), 320, 0, stream>>>(Qp, Kp, Vt, pe, Abf);
    gemm_out<<<dim3(8, 120), 256, 0, stream>>>(Abf, Wob, bo, out);
}